// Round 4
// baseline (335.198 us; speedup 1.0000x reference)
//
#include <hip/hip_runtime.h>
#include <math.h>

#define TT 128
#define SS 512
#define NB 256
#define START_TAG 126
#define STOP_TAG 127
#define NEGV -10000.0f

typedef float v2 __attribute__((ext_vector_type(2)));

__device__ __forceinline__ float rlane(float v, int lane) {
    return __int_as_float(__builtin_amdgcn_readlane(__float_as_int(v), lane));
}
__device__ __forceinline__ float wave_max(float v) {
#pragma unroll
    for (int off = 32; off >= 1; off >>= 1) v = fmaxf(v, __shfl_xor(v, off));
    return v;
}
__device__ __forceinline__ float wave_sum(float v) {
#pragma unroll
    for (int off = 32; off >= 1; off >>= 1) v += __shfl_xor(v, off);
    return v;
}

// One block per batch, 512 threads = 8 waves (2 per SIMD for latency hiding).
// Wave w owns k-sixteenth [16w, 16w+16); lane l owns tag pair (l, l+64).
// E2[j] = {exp(trans[l][16w+j]), exp(trans[l+64][16w+j])} in registers.
// Dot = 16 readlane + 16 packed fma. Partials exchanged via LDS, ONE barrier
// per step (parity double-buffered). Combine uses XOR-butterfly grouping
// ((acc+c1)+(c2+c3))+((c4+c5)+(c6+c7)) with c_m = part[w^m]: bitwise
// identical across waves (commutativity only), so the redundant per-wave
// normalizer M = fv[tag0] is consistent.
__global__ __launch_bounds__(512, 2) void crf_fwd_kernel(
    const float* __restrict__ feats,
    const float* __restrict__ trans,
    const int*   __restrict__ targets,
    float*       __restrict__ out)
{
    const int t = threadIdx.x;
    const int b = blockIdx.x;
    const int w = t >> 6;              // 0..7
    const int l = t & 63;
    const int kbase = (w & 3) << 4;    // lane base within the selected fv half

    __shared__ v2 part[2][8][64];      // [parity][wave][lane]
    __shared__ float redz[8];
    __shared__ float galpha;

    // ---- E fragment in registers ----
    v2 E2[16];
    {
        const float* r0 = trans + l * TT + (w << 4);
        const float* r1 = trans + (l + 64) * TT + (w << 4);
#pragma unroll
        for (int j = 0; j < 16; j += 4) {
            float4 a0 = *reinterpret_cast<const float4*>(r0 + j);
            float4 a1 = *reinterpret_cast<const float4*>(r1 + j);
            E2[j + 0] = (v2){__expf(a0.x), __expf(a1.x)};
            E2[j + 1] = (v2){__expf(a0.y), __expf(a1.y)};
            E2[j + 2] = (v2){__expf(a0.z), __expf(a1.z)};
            E2[j + 3] = (v2){__expf(a0.w), __expf(a1.w)};
        }
    }

    const size_t bst = (size_t)b * (SS * TT);
    const float* fb = feats + bst + l;

    // feats register pipeline, depth 4 (redundant across waves; L1 absorbs)
    float fx0 = fb[0 * TT], fy0 = fb[0 * TT + 64];
    float fx1 = fb[1 * TT], fy1 = fb[1 * TT + 64];
    float fx2 = fb[2 * TT], fy2 = fb[2 * TT + 64];
    float fx3 = fb[3 * TT], fy3 = fb[3 * TT + 64];

    // init: fv one-hot at START=126 (tag 126 = y-half, lane 62); M = 0
    float fvx = NEGV;
    float fvy = (l == 62) ? 0.f : NEGV;
    float M = 0.f;
    float psel = __expf((w < 4) ? fvx : fvy);   // exp(-1e4)->0, lane62 hi ->1

#define STEP(P)                                                          \
    {                                                                    \
        int sn = s + 4 + (P); sn = (sn < SS) ? sn : (SS - 1);            \
        float fnx = fb[(size_t)sn * TT];                                 \
        float fny = fb[(size_t)sn * TT + 64];                            \
        v2 A0 = (v2){0.f, 0.f}, A1 = (v2){0.f, 0.f};                     \
        _Pragma("unroll")                                                \
        for (int j = 0; j < 16; j += 2) {                                \
            float p0 = rlane(psel, kbase + j);                           \
            float p1 = rlane(psel, kbase + j + 1);                       \
            A0 = __builtin_elementwise_fma((v2){p0, p0}, E2[j], A0);     \
            A1 = __builtin_elementwise_fma((v2){p1, p1}, E2[j + 1], A1); \
        }                                                                \
        v2 acc = A0 + A1;                                                \
        part[P][w][l] = acc;                                             \
        __syncthreads();                                                 \
        v2 c1 = part[P][w ^ 1][l];                                       \
        v2 c2 = part[P][w ^ 2][l];                                       \
        v2 c3 = part[P][w ^ 3][l];                                       \
        v2 c4 = part[P][w ^ 4][l];                                       \
        v2 c5 = part[P][w ^ 5][l];                                       \
        v2 c6 = part[P][w ^ 6][l];                                       \
        v2 c7 = part[P][w ^ 7][l];                                       \
        v2 tot = ((acc + c1) + (c2 + c3)) + ((c4 + c5) + (c6 + c7));     \
        fvx = __logf(tot.x) + M + fx0;                                   \
        fvy = __logf(tot.y) + M + fy0;                                   \
        M = rlane(fvx, 0);                                               \
        psel = __expf(((w < 4) ? fvx : fvy) - M);                        \
        fx0 = fx1; fy0 = fy1; fx1 = fx2; fy1 = fy2;                      \
        fx2 = fx3; fy2 = fy3; fx3 = fnx; fy3 = fny;                      \
    }

    for (int s = 0; s < SS; s += 2) {
        STEP(0)
        STEP(1)
    }
#undef STEP

    // ---- gold path score: 512 threads = one s each ----
    {
        const int* tg = targets + b * SS;
        int cur  = tg[t];
        int prev = (t == 0) ? START_TAG : tg[t - 1];
        float g = trans[cur * TT + prev] + feats[bst + (size_t)t * TT + cur];
        if (t == 0) g += trans[STOP_TAG * TT + tg[SS - 1]];
        g = wave_sum(g);
        if (l == 0) redz[w] = g;
    }

    // ---- alpha = LSE(fv + trans[STOP,:]) on wave 0 (every wave has full fv) ----
    if (w == 0) {
        float vx = fvx + trans[STOP_TAG * TT + l];
        float vy = fvy + trans[STOP_TAG * TT + l + 64];
        float m = wave_max(fmaxf(vx, vy));
        float e = __expf(vx - m) + __expf(vy - m);
        e = wave_sum(e);
        if (l == 0) galpha = m + __logf(e);
    }
    __syncthreads();

    if (t == 0) {
        float gold = ((redz[0] + redz[1]) + (redz[2] + redz[3]))
                   + ((redz[4] + redz[5]) + (redz[6] + redz[7]));
        out[b] = gold - galpha;
    }
}

extern "C" void kernel_launch(void* const* d_in, const int* in_sizes, int n_in,
                              void* d_out, int out_size, void* d_ws, size_t ws_size,
                              hipStream_t stream) {
    const float* feats   = (const float*)d_in[0];
    const float* trans   = (const float*)d_in[1];
    const int*   targets = (const int*)d_in[2];
    float*       out     = (float*)d_out;
    crf_fwd_kernel<<<dim3(NB), dim3(512), 0, stream>>>(feats, trans, targets, out);
}

// Round 5
// 264.090 us; speedup vs baseline: 1.2693x; 1.2693x over previous
//
#include <hip/hip_runtime.h>
#include <math.h>

#define TT 128
#define SS 512
#define NB 256
#define START_TAG 126
#define STOP_TAG 127
#define NEGV -10000.0f

__device__ __forceinline__ float rlane(float v, int lane) {
    return __int_as_float(__builtin_amdgcn_readlane(__float_as_int(v), lane));
}
__device__ __forceinline__ float wave_max(float v) {
#pragma unroll
    for (int off = 32; off >= 1; off >>= 1) v = fmaxf(v, __shfl_xor(v, off));
    return v;
}
__device__ __forceinline__ float wave_sum(float v) {
#pragma unroll
    for (int off = 32; off >= 1; off >>= 1) v += __shfl_xor(v, off);
    return v;
}

// One block per batch, 512 threads = 8 waves.
// Z = LSE_j(A_256[j] + B_256[j]): waves 0-3 run the FORWARD chain (steps
// 0..255), waves 4-7 run the independent BACKWARD chain (steps 511..256)
// simultaneously -- 2x parallelism in S that lockstep k-splitting can't give.
// Each group is the R3 shape: wave g owns k-quarter [32g,32g+32), lane l owns
// tag pair (l, l+64), E fragment in registers, dot = 32 readlane + 64 fma,
// partials exchanged via LDS with ONE shared barrier per step (parity
// double-buffered; both groups hit the same barrier 256 times).
// Fwd: state = log(tot) + M + f_s;        p = exp(state - M')
// Bwd: state = log(tot) + M;              p = exp(state + f_k - M')
// unified via 0/1 selector fmas (wave-uniform -> no divergence in loop).
__global__ __launch_bounds__(512, 2) void crf_fwd_kernel(
    const float* __restrict__ feats,
    const float* __restrict__ trans,
    const int*   __restrict__ targets,
    float*       __restrict__ out)
{
    const int t = threadIdx.x;
    const int b = blockIdx.x;
    const int w = t >> 6;             // 0..7
    const int l = t & 63;
    const int group = w >> 2;         // 0 = forward, 1 = backward
    const int g = w & 3;              // wave id within group
    const int base = (g & 1) << 5;    // readlane base within selected half
    const float gsel = group ? 0.f : 1.f;   // emission into state (fwd)
    const float gnot = group ? 1.f : 0.f;   // emission into p-arg (bwd)

    __shared__ float2 part[2][8][64];
    __shared__ float redz[8];
    __shared__ float galpha;

    // ---- E fragment in registers ----
    // fwd: E2[k].{x,y} = exp(trans[l][32g+k]), exp(trans[l+64][32g+k])
    // bwd: E2[k].{x,y} = exp(trans[32g+k][l]), exp(trans[32g+k][l+64])  (E^T)
    float2 E2[32];
    if (group == 0) {
        const float* r0 = trans + l * TT + (g << 5);
        const float* r1 = trans + (l + 64) * TT + (g << 5);
#pragma unroll
        for (int k = 0; k < 32; k += 4) {
            float4 a0 = *reinterpret_cast<const float4*>(r0 + k);
            float4 a1 = *reinterpret_cast<const float4*>(r1 + k);
            E2[k + 0] = make_float2(__expf(a0.x), __expf(a1.x));
            E2[k + 1] = make_float2(__expf(a0.y), __expf(a1.y));
            E2[k + 2] = make_float2(__expf(a0.z), __expf(a1.z));
            E2[k + 3] = make_float2(__expf(a0.w), __expf(a1.w));
        }
    } else {
        const float* rc = trans + (g << 5) * TT + l;
#pragma unroll
        for (int k = 0; k < 32; ++k) {
            E2[k] = make_float2(__expf(rc[k * TT]), __expf(rc[k * TT + 64]));
        }
    }

    const size_t bst = (size_t)b * (SS * TT);
    const float* fb = feats + bst + l;

    // feats pipeline: f0 = emission consumed at the NEXT combine.
    // fwd pipeline indices {0,1,2,3}; bwd {510,509,508,507} (511 used at init).
#define FIDX(i) (group ? (510 - (i)) : (i))
    float fx0 = fb[(size_t)FIDX(0) * TT], fy0 = fb[(size_t)FIDX(0) * TT + 64];
    float fx1 = fb[(size_t)FIDX(1) * TT], fy1 = fb[(size_t)FIDX(1) * TT + 64];
    float fx2 = fb[(size_t)FIDX(2) * TT], fy2 = fb[(size_t)FIDX(2) * TT + 64];
    float fx3 = fb[(size_t)FIDX(3) * TT], fy3 = fb[(size_t)FIDX(3) * TT + 64];
    const int ii = group ? 511 : 0;
    float fInx = fb[(size_t)ii * TT], fIny = fb[(size_t)ii * TT + 64];
#undef FIDX

    // ---- init state ----
    float statex, statey;
    if (group == 0) {
        statex = NEGV;
        statey = (l == 62) ? 0.f : NEGV;   // START=126 = y-half lane 62
    } else {
        statex = trans[STOP_TAG * TT + l];
        statey = trans[STOP_TAG * TT + l + 64];
    }
    float argx = fmaf(fInx, gnot, statex);
    float argy = fmaf(fIny, gnot, statey);
    float M = group ? rlane(argx, 0) : 0.f;
    float psel = __expf(((g < 2) ? argx : argy) - M);

#define STEP(P)                                                           \
    {                                                                     \
        int sn = group ? (506 - s - (P)) : (s + 4 + (P));                 \
        float fnx = fb[(size_t)sn * TT];                                  \
        float fny = fb[(size_t)sn * TT + 64];                             \
        float ax = 0.f, ay = 0.f;                                         \
        _Pragma("unroll")                                                 \
        for (int k = 0; k < 32; ++k) {                                    \
            float pk = rlane(psel, base + k);                             \
            ax = fmaf(pk, E2[k].x, ax);                                   \
            ay = fmaf(pk, E2[k].y, ay);                                   \
        }                                                                 \
        part[P][w][l] = make_float2(ax, ay);                              \
        __syncthreads();                                                  \
        float2 c1 = part[P][w ^ 1][l];                                    \
        float2 c2 = part[P][w ^ 2][l];                                    \
        float2 c3 = part[P][w ^ 3][l];                                    \
        float tx = (ax + c1.x) + (c2.x + c3.x);                           \
        float ty = (ay + c1.y) + (c2.y + c3.y);                           \
        statex = fmaf(fx0, gsel, __logf(tx) + M);                         \
        statey = fmaf(fy0, gsel, __logf(ty) + M);                         \
        float agx = fmaf(fx0, gnot, statex);                              \
        float agy = fmaf(fy0, gnot, statey);                              \
        M = rlane(agx, 0);                                                \
        psel = __expf(((g < 2) ? agx : agy) - M);                         \
        fx0 = fx1; fy0 = fy1; fx1 = fx2; fy1 = fy2;                       \
        fx2 = fx3; fy2 = fy3; fx3 = fnx; fy3 = fny;                       \
    }

    for (int s = 0; s < SS / 2; s += 2) {
        STEP(0)
        STEP(1)
    }
#undef STEP

    // ---- exchange B_256 (wave 4) -> combine with A_256 (wave 0) ----
    __syncthreads();
    if (w == 4) part[0][0][l] = make_float2(statex, statey);

    // ---- gold path score: 512 threads = one s each ----
    {
        const int* tg = targets + b * SS;
        int cur  = tg[t];
        int prev = (t == 0) ? START_TAG : tg[t - 1];
        float gs = trans[cur * TT + prev] + feats[bst + (size_t)t * TT + cur];
        if (t == 0) gs += trans[STOP_TAG * TT + tg[SS - 1]];
        gs = wave_sum(gs);
        if (l == 0) redz[w] = gs;
    }
    __syncthreads();

    if (w == 0) {
        float2 bb = part[0][0][l];
        float vx = statex + bb.x;
        float vy = statey + bb.y;
        float m = wave_max(fmaxf(vx, vy));
        float e = __expf(vx - m) + __expf(vy - m);
        e = wave_sum(e);
        if (l == 0) galpha = m + __logf(e);
    }
    __syncthreads();

    if (t == 0) {
        float gold = ((redz[0] + redz[1]) + (redz[2] + redz[3]))
                   + ((redz[4] + redz[5]) + (redz[6] + redz[7]));
        out[b] = gold - galpha;
    }
}

extern "C" void kernel_launch(void* const* d_in, const int* in_sizes, int n_in,
                              void* d_out, int out_size, void* d_ws, size_t ws_size,
                              hipStream_t stream) {
    const float* feats   = (const float*)d_in[0];
    const float* trans   = (const float*)d_in[1];
    const int*   targets = (const int*)d_in[2];
    float*       out     = (float*)d_out;
    crf_fwd_kernel<<<dim3(NB), dim3(512), 0, stream>>>(feats, trans, targets, out);
}

// Round 7
// 234.707 us; speedup vs baseline: 1.4282x; 1.1252x over previous
//
#include <hip/hip_runtime.h>

#define TT 128
#define SS 512
#define NB 256
#define START_TAG 126
#define STOP_TAG 127
#define NEGV -10000.0f
#define LOG2E 1.4426950408889634f
#define LN2   0.6931471805599453f

typedef float v2 __attribute__((ext_vector_type(2)));

__device__ __forceinline__ float ex2(float x) { return __builtin_amdgcn_exp2f(x); }   // 2^x
__device__ __forceinline__ float lg2(float x) { return __builtin_amdgcn_logf(x); }    // log2(x)
__device__ __forceinline__ float exn(float x) { return __builtin_amdgcn_exp2f(x * LOG2E); } // e^x

__device__ __forceinline__ float rlane(float v, int lane) {
    return __int_as_float(__builtin_amdgcn_readlane(__float_as_int(v), lane));
}
__device__ __forceinline__ float wave_max(float v) {
#pragma unroll
    for (int off = 32; off >= 1; off >>= 1) v = fmaxf(v, __shfl_xor(v, off));
    return v;
}
__device__ __forceinline__ float wave_sum(float v) {
#pragma unroll
    for (int off = 32; off >= 1; off >>= 1) v += __shfl_xor(v, off);
    return v;
}

// One block per batch, 512 threads = 8 waves. Waves 0-3: forward chain
// (steps 0..255); waves 4-7: backward chain (steps 511..256); Z = LSE(A+B).
// All state kept in LOG2 domain (emissions pre-scaled by log2e at load).
// Broadcast without readlane waterfall: every wave holds the full state
// post-combine, writes its own private p copy to LDS (per-wave DS is
// in-order => no barrier needed), dot reads its k-quarter via wave-UNIFORM
// ds_read_b128 broadcasts (LDS pipe, not VALU). MACs = 32 v_pk_fma_f32 with
// 4-way acc split. One barrier per step (parity double-buffered partials).
__global__ __launch_bounds__(512, 2) void crf_fwd_kernel(
    const float* __restrict__ feats,
    const float* __restrict__ trans,
    const int*   __restrict__ targets,
    float*       __restrict__ out)
{
    const int t = threadIdx.x;
    const int b = blockIdx.x;
    const int w = t >> 6;             // 0..7
    const int l = t & 63;
    const int group = w >> 2;         // 0 = forward, 1 = backward
    const int g = w & 3;              // wave id within group (k-quarter)
    const float gsel = group ? 0.f : 1.f;   // emission folded into state (fwd)
    const float gnot = group ? 1.f : 0.f;   // emission folded into p-arg (bwd)

    __shared__ __align__(16) float pbuf[8][128];  // per-wave private p copy
    __shared__ v2 part[2][8][64];                 // [parity][wave][lane]
    __shared__ float redz[8];
    __shared__ float galpha;

    // ---- E fragment in registers (linear domain: e^trans) ----
    // fwd: E2[k] = {exp(trans[l][32g+k]), exp(trans[l+64][32g+k])}
    // bwd: E2[k] = {exp(trans[32g+k][l]), exp(trans[32g+k][l+64])}  (E^T)
    v2 E2[32];
    if (group == 0) {
        const float* r0 = trans + l * TT + (g << 5);
        const float* r1 = trans + (l + 64) * TT + (g << 5);
#pragma unroll
        for (int k = 0; k < 32; k += 4) {
            float4 a0 = *reinterpret_cast<const float4*>(r0 + k);
            float4 a1 = *reinterpret_cast<const float4*>(r1 + k);
            E2[k + 0] = (v2){exn(a0.x), exn(a1.x)};
            E2[k + 1] = (v2){exn(a0.y), exn(a1.y)};
            E2[k + 2] = (v2){exn(a0.z), exn(a1.z)};
            E2[k + 3] = (v2){exn(a0.w), exn(a1.w)};
        }
    } else {
        const float* rc = trans + (g << 5) * TT + l;
#pragma unroll
        for (int k = 0; k < 32; ++k) {
            E2[k] = (v2){exn(rc[k * TT]), exn(rc[k * TT + 64])};
        }
    }

    const size_t bst = (size_t)b * (SS * TT);
    const float* fb = feats + bst + l;
    float* pwr = &pbuf[w][l];                                  // own p slot
    const float4* pq4 = reinterpret_cast<const float4*>(&pbuf[w][g << 5]);

    // feats pipeline (log2-scaled). fwd: 0,1,2,3 ; bwd: 510,509,508,507.
#define FIDX(i) (group ? (510 - (i)) : (i))
    float fx0 = fb[(size_t)FIDX(0) * TT] * LOG2E, fy0 = fb[(size_t)FIDX(0) * TT + 64] * LOG2E;
    float fx1 = fb[(size_t)FIDX(1) * TT] * LOG2E, fy1 = fb[(size_t)FIDX(1) * TT + 64] * LOG2E;
    float fx2 = fb[(size_t)FIDX(2) * TT] * LOG2E, fy2 = fb[(size_t)FIDX(2) * TT + 64] * LOG2E;
    float fx3 = fb[(size_t)FIDX(3) * TT] * LOG2E, fy3 = fb[(size_t)FIDX(3) * TT + 64] * LOG2E;
    const int ii = group ? 511 : 0;
    float fInx = fb[(size_t)ii * TT] * LOG2E, fIny = fb[(size_t)ii * TT + 64] * LOG2E;
#undef FIDX

    // ---- init state (log2 scale) ----
    float statex, statey;
    if (group == 0) {
        statex = NEGV;
        statey = (l == 62) ? 0.f : NEGV;            // START=126 = y-half lane 62
    } else {
        statex = trans[STOP_TAG * TT + l] * LOG2E;
        statey = trans[STOP_TAG * TT + l + 64] * LOG2E;
    }
    float argx = fmaf(fInx, gnot, statex);
    float argy = fmaf(fIny, gnot, statey);
    float M = group ? rlane(argx, 0) : 0.f;
    pwr[0]  = ex2(argx - M);
    pwr[64] = ex2(argy - M);

#define STEP(P)                                                             \
    {                                                                       \
        int sn = group ? (506 - s - (P)) : (s + 4 + (P));                   \
        float fnx = fb[(size_t)sn * TT] * LOG2E;                            \
        float fny = fb[(size_t)sn * TT + 64] * LOG2E;                       \
        v2 a0 = (v2){0.f, 0.f}, a1 = a0, a2 = a0, a3 = a0;                  \
        _Pragma("unroll")                                                   \
        for (int j = 0; j < 8; ++j) {                                       \
            float4 q = pq4[j];                                              \
            a0 = __builtin_elementwise_fma((v2){q.x, q.x}, E2[4*j+0], a0);  \
            a1 = __builtin_elementwise_fma((v2){q.y, q.y}, E2[4*j+1], a1);  \
            a2 = __builtin_elementwise_fma((v2){q.z, q.z}, E2[4*j+2], a2);  \
            a3 = __builtin_elementwise_fma((v2){q.w, q.w}, E2[4*j+3], a3);  \
        }                                                                   \
        v2 acc = (a0 + a1) + (a2 + a3);                                     \
        part[P][w][l] = acc;                                                \
        __syncthreads();                                                    \
        v2 c1 = part[P][w ^ 1][l];                                          \
        v2 c2 = part[P][w ^ 2][l];                                          \
        v2 c3 = part[P][w ^ 3][l];                                          \
        v2 tot = (acc + c1) + (c2 + c3);                                    \
        statex = fmaf(fx0, gsel, lg2(tot.x) + M);                           \
        statey = fmaf(fy0, gsel, lg2(tot.y) + M);                           \
        float agx = fmaf(fx0, gnot, statex);                                \
        float agy = fmaf(fy0, gnot, statey);                                \
        M = rlane(agx, 0);                                                  \
        pwr[0]  = ex2(agx - M);                                             \
        pwr[64] = ex2(agy - M);                                             \
        fx0 = fx1; fy0 = fy1; fx1 = fx2; fy1 = fy2;                         \
        fx2 = fx3; fy2 = fy3; fx3 = fnx; fy3 = fny;                         \
    }

    for (int s = 0; s < SS / 2; s += 2) {
        STEP(0)
        STEP(1)
    }
#undef STEP

    // ---- exchange B_256 (wave 4) -> combine with A_256 (wave 0) ----
    __syncthreads();
    if (w == 4) part[0][0][l] = (v2){statex, statey};

    // ---- gold path score (natural units): 512 threads = one s each ----
    {
        const int* tg = targets + b * SS;
        int cur  = tg[t];
        int prev = (t == 0) ? START_TAG : tg[t - 1];
        float gs = trans[cur * TT + prev] + feats[bst + (size_t)t * TT + cur];
        if (t == 0) gs += trans[STOP_TAG * TT + tg[SS - 1]];
        gs = wave_sum(gs);
        if (l == 0) redz[w] = gs;
    }
    __syncthreads();

    if (w == 0) {
        v2 bb = part[0][0][l];
        float vx = statex + bb.x;         // log2 scale
        float vy = statey + bb.y;
        float m = wave_max(fmaxf(vx, vy));
        float e = ex2(vx - m) + ex2(vy - m);
        e = wave_sum(e);
        if (l == 0) galpha = (m + lg2(e)) * LN2;   // back to natural
    }
    __syncthreads();

    if (t == 0) {
        float gold = ((redz[0] + redz[1]) + (redz[2] + redz[3]))
                   + ((redz[4] + redz[5]) + (redz[6] + redz[7]));
        out[b] = gold - galpha;
    }
}

extern "C" void kernel_launch(void* const* d_in, const int* in_sizes, int n_in,
                              void* d_out, int out_size, void* d_ws, size_t ws_size,
                              hipStream_t stream) {
    const float* feats   = (const float*)d_in[0];
    const float* trans   = (const float*)d_in[1];
    const int*   targets = (const int*)d_in[2];
    float*       out     = (float*)d_out;
    crf_fwd_kernel<<<dim3(NB), dim3(512), 0, stream>>>(feats, trans, targets, out);
}